// Round 11
// baseline (411.847 us; speedup 1.0000x reference)
//
#include <hip/hip_runtime.h>
#include <hip/hip_fp16.h>

#define NROWS   16384
#define NCOL    4096
#define NSTAGES 12
#define NPAIRS  2048
#define RPB     2   // rows per block (32 KB LDS) — proven shape

// staging swizzle (validated R1-R10) and interleaved-exchange swizzle (new):
// swzI XORs float2-position bits [3:1] with bits [6:4] -> b64 writes hit 16
// bank-pairs depth-4 (floor), b128 reads hit 8 bank-groups x 8 lanes (floor).
__device__ __forceinline__ int swzI(int P) {
  return P ^ (((P >> 4) & 7) << 1);
}

// pair index needed by lane t, stage s, sub-pair p (matches butterfly layouts)
__device__ __forceinline__ int pair_idx(int s, int t, int p) {
  int thi = t >> 4, tlo = t & 15;
  return (s < 4) ? (t * 8 + p) : (s < 8) ? (thi * 128 + p * 16 + tlo) : (p * 256 + t);
}

// fp16 packed table: tabq[(s*2+h)*256 + t] = uint4 of 4 half2 {cos,sin},
// pairs p = 4h..4h+3 for lane t, stage s. fp16 accuracy validated R6-R10
// (absmax 0.031 < 0.1175 threshold).
__global__ void cs_table_kernel(const float* __restrict__ ang, uint4* __restrict__ tabq) {
  int tid = blockIdx.x * blockDim.x + threadIdx.x;
  if (tid >= NSTAGES * 2 * 256) return;
  int s = tid >> 9;
  int h = (tid >> 8) & 1;
  int t = tid & 255;
  unsigned r[4];
#pragma unroll
  for (int e = 0; e < 4; ++e) {
    int pr = pair_idx(s, t, 4 * h + e);
    float sv, cv;
    sincosf(ang[s * NPAIRS + pr], &sv, &cv);
    __half2 hh = __floats2half2_rn(cv, sv);
    r[e] = *reinterpret_cast<unsigned*>(&hh);
  }
  tabq[tid] = make_uint4(r[0], r[1], r[2], r[3]);
}

__device__ __forceinline__ float2 h2f(unsigned u) {
  __half2 h = *reinterpret_cast<__half2*>(&u);
  return __half22float2(h);
}

// wave-lockstep LDS fence (validated R5-R10)
__device__ __forceinline__ void wave_lds_fence() {
  asm volatile("s_waitcnt lgkmcnt(0)" ::: "memory");
  __builtin_amdgcn_sched_barrier(0);
}

// block barrier WITHOUT vmcnt drain (validated R6-R10)
__device__ __forceinline__ void block_barrier_lgkm() {
  asm volatile("s_waitcnt lgkmcnt(0)" ::: "memory");
  __builtin_amdgcn_sched_barrier(0);
  __builtin_amdgcn_s_barrier();
  __builtin_amdgcn_sched_barrier(0);
}

// table prefetch for one stage (2 dwordx4); no-op in fallback mode
template <bool TAB>
__device__ __forceinline__ void fetch_stage(const uint4* __restrict__ tabq, int s, int t,
                                            uint4& qa, uint4& qb) {
  if constexpr (TAB) {
    qa = tabq[(s * 2 + 0) * 256 + t];
    qb = tabq[(s * 2 + 1) * 256 + t];
  }
}

// one butterfly stage on 2 rows packed as float2 (SLP-vectorizable f32 pairs)
template <bool TAB>
__device__ __forceinline__ void stage_math(int sg, int sl, uint4 qa, uint4 qb,
                                           const float* __restrict__ ang, int t,
                                           float2* v2) {
  const int d = 1 << sl;
  const unsigned aw[8] = {qa.x, qa.y, qa.z, qa.w, qb.x, qb.y, qb.z, qb.w};
#pragma unroll
  for (int p = 0; p < 8; ++p) {
    float2 A;
    if constexpr (TAB) {
      A = h2f(aw[p]);
    } else {
      float sv, cv;
      sincosf(ang[sg * NPAIRS + pair_idx(sg, t, p)], &sv, &cv);
      A = make_float2(cv, sv);
    }
    const int j0 = ((p >> sl) << (sl + 1)) | (p & (d - 1));
    const int j1 = j0 + d;
    float2 v0 = v2[j0], v1 = v2[j1];
    v2[j0] = make_float2(A.x * v0.x - A.y * v1.x, A.x * v0.y - A.y * v1.y);
    v2[j1] = make_float2(A.y * v0.x + A.x * v1.x, A.y * v0.y + A.x * v1.y);
  }
}

template <bool TAB>
__global__ __launch_bounds__(256, 5) void butterfly_kernel(
    const float* __restrict__ x, const uint4* __restrict__ tabq,
    const float* __restrict__ ang, float* __restrict__ out) {
  // one 32 KB buffer, two typed views:
  //  staging view: float [2][4096] (row-separate, b128 ops)
  //  exchange view: float2 [4096] (rows interleaved, b64 writes / b128 reads)
  __shared__ __align__(16) float lds_raw[2 * NCOL];
  float (*lds)[NCOL] = reinterpret_cast<float (*)[NCOL]>(lds_raw);
  float2* ldsI = reinterpret_cast<float2*>(lds_raw);

  const int t   = threadIdx.x;
  const int w   = t >> 6;   // wave id
  const int l   = t & 63;   // lane id
  const int thi = t >> 4;
  const int tlo = t & 15;
  const size_t row0 = (size_t)blockIdx.x * RPB;

  // ---- staging global loads FIRST (oldest vmcnt entries) ----
  float4 st[RPB][4];
#pragma unroll
  for (int r = 0; r < RPB; ++r) {
    const float4* row4 = reinterpret_cast<const float4*>(x + (row0 + r) * NCOL);
#pragma unroll
    for (int k = 0; k < 4; ++k)
      st[r][k] = row4[256 * w + 64 * k + l];
  }

  // ---- phase-1 table prefetch: overlaps staging HBM latency ----
  uint4 qa0, qb0, qa1, qb1, qa2, qb2, qa3, qb3;
  fetch_stage<TAB>(tabq, 0, t, qa0, qb0);
  fetch_stage<TAB>(tabq, 1, t, qa1, qb1);
  fetch_stage<TAB>(tabq, 2, t, qa2, qb2);
  fetch_stage<TAB>(tabq, 3, t, qa3, qb3);

  // ---- stage to LDS: wave-local, swizzled sigma(c)=c^((c>>3)&7) ----
#pragma unroll
  for (int r = 0; r < RPB; ++r) {
#pragma unroll
    for (int k = 0; k < 4; ++k) {
      const int c  = 256 * w + 64 * k + l;
      const int cs = c ^ ((c >> 3) & 7);
      *reinterpret_cast<float4*>(&lds[r][cs * 4]) = st[r][k];
    }
  }
  wave_lds_fence();

  // ---- phase-1 fragment read, rows packed into float2 ----
  float2 v2[16];
#pragma unroll
  for (int k = 0; k < 4; ++k) {
    int ba = (t * 64 + k * 16) ^ (((t >> 1) & 7) << 4);  // swizzled byte addr
    float4 q0 = *reinterpret_cast<const float4*>(
        reinterpret_cast<const char*>(&lds[0][0]) + ba);
    float4 q1 = *reinterpret_cast<const float4*>(
        reinterpret_cast<const char*>(&lds[1][0]) + ba);
    v2[4 * k + 0] = make_float2(q0.x, q1.x);
    v2[4 * k + 1] = make_float2(q0.y, q1.y);
    v2[4 * k + 2] = make_float2(q0.z, q1.z);
    v2[4 * k + 3] = make_float2(q0.w, q1.w);
  }

  // ---- phase 1: stages 0..3 ----
  stage_math<TAB>(0, 0, qa0, qb0, ang, t, v2);
  stage_math<TAB>(1, 1, qa1, qb1, ang, t, v2);
  stage_math<TAB>(2, 2, qa2, qb2, ang, t, v2);
  stage_math<TAB>(3, 3, qa3, qb3, ang, t, v2);

  // ---- phase-2 table prefetch: L2 latency hides under exchange 1 ----
  uint4 pa0, pb0, pa1, pb1, pa2, pb2, pa3, pb3;
  fetch_stage<TAB>(tabq, 4, t, pa0, pb0);
  fetch_stage<TAB>(tabq, 5, t, pa1, pb1);
  fetch_stage<TAB>(tabq, 6, t, pa2, pb2);
  fetch_stage<TAB>(tabq, 7, t, pa3, pb3);

  // ---- exchange 1 (wave-local): b64 writes to position thi*256+j*16+tlo,
  //      b128 reads of positions t*16+2m,2m+1 (swzI on both sides) ----
#pragma unroll
  for (int j = 0; j < 16; ++j)
    ldsI[swzI(thi * 256 + j * 16 + tlo)] = v2[j];
  wave_lds_fence();
#pragma unroll
  for (int m = 0; m < 8; ++m) {
    float4 q = *reinterpret_cast<const float4*>(&ldsI[swzI(t * 16 + 2 * m)]);
    v2[2 * m + 0] = make_float2(q.x, q.y);
    v2[2 * m + 1] = make_float2(q.z, q.w);
  }

  // ---- phase 2: stages 4..7 ----
  stage_math<TAB>(4, 0, pa0, pb0, ang, t, v2);
  stage_math<TAB>(5, 1, pa1, pb1, ang, t, v2);
  stage_math<TAB>(6, 2, pa2, pb2, ang, t, v2);
  stage_math<TAB>(7, 3, pa3, pb3, ang, t, v2);

  // ---- exchange 2 (cross-wave): b64 writes to position j*256+tlo*16+thi ----
  block_barrier_lgkm();   // all waves done reading exchange-1 data
#pragma unroll
  for (int j = 0; j < 16; ++j)
    ldsI[swzI(j * 256 + tlo * 16 + thi)] = v2[j];

  // ---- phase-3 table prefetch: issued here so its registers are not live
  //      during phase 2 (fits launch_bounds 5); latency hides under barrier ----
  uint4 ra0, rb0, ra1, rb1, ra2, rb2, ra3, rb3;
  fetch_stage<TAB>(tabq, 8, t, ra0, rb0);
  fetch_stage<TAB>(tabq, 9, t, ra1, rb1);
  fetch_stage<TAB>(tabq, 10, t, ra2, rb2);
  fetch_stage<TAB>(tabq, 11, t, ra3, rb3);

  block_barrier_lgkm();   // cross-writes visible
#pragma unroll
  for (int m = 0; m < 8; ++m) {
    float4 q = *reinterpret_cast<const float4*>(&ldsI[swzI(t * 16 + 2 * m)]);
    v2[2 * m + 0] = make_float2(q.x, q.y);
    v2[2 * m + 1] = make_float2(q.z, q.w);
  }

  // ---- phase 3: stages 8..11 ----
  stage_math<TAB>(8, 0, ra0, rb0, ang, t, v2);
  stage_math<TAB>(9, 1, ra1, rb1, ang, t, v2);
  stage_math<TAB>(10, 2, ra2, rb2, ang, t, v2);
  stage_math<TAB>(11, 3, ra3, rb3, ang, t, v2);

  // ---- store (elem i*256 + t: lanes contiguous, coalesced) ----
  float* orow0 = out + (row0 + 0) * NCOL;
  float* orow1 = out + (row0 + 1) * NCOL;
#pragma unroll
  for (int i = 0; i < 16; ++i) {
    orow0[i * 256 + t] = v2[i].x;
    orow1[i * 256 + t] = v2[i].y;
  }
}

extern "C" void kernel_launch(void* const* d_in, const int* in_sizes, int n_in,
                              void* d_out, int out_size, void* d_ws, size_t ws_size,
                              hipStream_t stream) {
  const float* x   = (const float*)d_in[0];
  const float* ang = (const float*)d_in[1];
  float* out       = (float*)d_out;

  const size_t tab_bytes = (size_t)NSTAGES * 2 * 256 * sizeof(uint4);  // 96 KB
  const int nblocks = NROWS / RPB;  // 8192

  if (ws_size >= tab_bytes) {
    uint4* tabq = (uint4*)d_ws;
    cs_table_kernel<<<(NSTAGES * 2 * 256 + 255) / 256, 256, 0, stream>>>(ang, tabq);
    butterfly_kernel<true><<<nblocks, 256, 0, stream>>>(x, tabq, nullptr, out);
  } else {
    butterfly_kernel<false><<<nblocks, 256, 0, stream>>>(x, nullptr, ang, out);
  }
}

// Round 13
// 276.709 us; speedup vs baseline: 1.4884x; 1.4884x over previous
//
#include <hip/hip_runtime.h>
#include <hip/hip_fp16.h>

#define NROWS   16384
#define NCOL    4096
#define NSTAGES 12
#define NPAIRS  2048
#define RPB     2   // rows per block (32 KB LDS) — proven shape

// staging swizzle (validated R1-R11) and interleaved-exchange swizzle
// (algebra validated R11): swzI XORs float2-position bits [3:1] with [6:4].
__device__ __forceinline__ int swzI(int P) {
  return P ^ (((P >> 4) & 7) << 1);
}

// pair index needed by lane t, stage s, sub-pair p (matches butterfly layouts)
__device__ __forceinline__ int pair_idx(int s, int t, int p) {
  int thi = t >> 4, tlo = t & 15;
  return (s < 4) ? (t * 8 + p) : (s < 8) ? (thi * 128 + p * 16 + tlo) : (p * 256 + t);
}

// fp16 packed table: tabq[(s*2+h)*256 + t] = uint4 of 4 half2 {cos,sin},
// pairs p = 4h..4h+3 for lane t, stage s. fp16 accuracy validated R6-R11
// (absmax 0.031 < 0.1175 threshold).
__global__ void cs_table_kernel(const float* __restrict__ ang, uint4* __restrict__ tabq) {
  int tid = blockIdx.x * blockDim.x + threadIdx.x;
  if (tid >= NSTAGES * 2 * 256) return;
  int s = tid >> 9;
  int h = (tid >> 8) & 1;
  int t = tid & 255;
  unsigned r[4];
#pragma unroll
  for (int e = 0; e < 4; ++e) {
    int pr = pair_idx(s, t, 4 * h + e);
    float sv, cv;
    sincosf(ang[s * NPAIRS + pr], &sv, &cv);
    __half2 hh = __floats2half2_rn(cv, sv);
    r[e] = *reinterpret_cast<unsigned*>(&hh);
  }
  tabq[tid] = make_uint4(r[0], r[1], r[2], r[3]);
}

__device__ __forceinline__ float2 h2f(unsigned u) {
  __half2 h = *reinterpret_cast<__half2*>(&u);
  return __half22float2(h);
}

// wave-lockstep LDS fence (validated R5-R11)
__device__ __forceinline__ void wave_lds_fence() {
  asm volatile("s_waitcnt lgkmcnt(0)" ::: "memory");
  __builtin_amdgcn_sched_barrier(0);
}

// block barrier WITHOUT vmcnt drain (validated R6-R11)
__device__ __forceinline__ void block_barrier_lgkm() {
  asm volatile("s_waitcnt lgkmcnt(0)" ::: "memory");
  __builtin_amdgcn_sched_barrier(0);
  __builtin_amdgcn_s_barrier();
  __builtin_amdgcn_sched_barrier(0);
}

// table prefetch for one stage (2 dwordx4); no-op in fallback mode
template <bool TAB>
__device__ __forceinline__ void fetch_stage(const uint4* __restrict__ tabq, int s, int t,
                                            uint4& qa, uint4& qb) {
  if constexpr (TAB) {
    qa = tabq[(s * 2 + 0) * 256 + t];
    qb = tabq[(s * 2 + 1) * 256 + t];
  }
}

// one butterfly stage on 2 rows packed as float2 (SLP-vectorizable f32 pairs)
template <bool TAB>
__device__ __forceinline__ void stage_math(int sg, int sl, uint4 qa, uint4 qb,
                                           const float* __restrict__ ang, int t,
                                           float2* v2) {
  const int d = 1 << sl;
  const unsigned aw[8] = {qa.x, qa.y, qa.z, qa.w, qb.x, qb.y, qb.z, qb.w};
#pragma unroll
  for (int p = 0; p < 8; ++p) {
    float2 A;
    if constexpr (TAB) {
      A = h2f(aw[p]);
    } else {
      float sv, cv;
      sincosf(ang[sg * NPAIRS + pair_idx(sg, t, p)], &sv, &cv);
      A = make_float2(cv, sv);
    }
    const int j0 = ((p >> sl) << (sl + 1)) | (p & (d - 1));
    const int j1 = j0 + d;
    float2 v0 = v2[j0], v1 = v2[j1];
    v2[j0] = make_float2(A.x * v0.x - A.y * v1.x, A.x * v0.y - A.y * v1.y);
    v2[j1] = make_float2(A.y * v0.x + A.x * v1.x, A.y * v0.y + A.x * v1.y);
  }
}

template <bool TAB>
__global__ __launch_bounds__(256, 4) void butterfly_kernel(
    const float* __restrict__ x, const uint4* __restrict__ tabq,
    const float* __restrict__ ang, float* __restrict__ out) {
  // one 32 KB buffer, two typed views:
  //  staging view: float [2][4096] (row-separate, b128 ops)
  //  exchange view: float2 [4096] (rows interleaved, b64 writes / b128 reads)
  // NOTE: wave w's exchange region (bytes [8192w,+8192)) overlaps OTHER
  // waves' staging regions -> a block barrier is REQUIRED before the
  // exchange-1 writes (R12 post-mortem: missing barrier = race).
  __shared__ __align__(16) float lds_raw[2 * NCOL];
  float (*lds)[NCOL] = reinterpret_cast<float (*)[NCOL]>(lds_raw);
  float2* ldsI = reinterpret_cast<float2*>(lds_raw);

  const int t   = threadIdx.x;
  const int w   = t >> 6;   // wave id
  const int l   = t & 63;   // lane id
  const int thi = t >> 4;
  const int tlo = t & 15;
  const size_t row0 = (size_t)blockIdx.x * RPB;

  // ---- staging global loads FIRST (oldest vmcnt entries) ----
  float4 st[RPB][4];
#pragma unroll
  for (int r = 0; r < RPB; ++r) {
    const float4* row4 = reinterpret_cast<const float4*>(x + (row0 + r) * NCOL);
#pragma unroll
    for (int k = 0; k < 4; ++k)
      st[r][k] = row4[256 * w + 64 * k + l];
  }

  // ---- phase-1 table prefetch: overlaps staging HBM latency ----
  uint4 qa0, qb0, qa1, qb1, qa2, qb2, qa3, qb3;
  fetch_stage<TAB>(tabq, 0, t, qa0, qb0);
  fetch_stage<TAB>(tabq, 1, t, qa1, qb1);
  fetch_stage<TAB>(tabq, 2, t, qa2, qb2);
  fetch_stage<TAB>(tabq, 3, t, qa3, qb3);

  // ---- stage to LDS: wave-local, swizzled sigma(c)=c^((c>>3)&7) ----
#pragma unroll
  for (int r = 0; r < RPB; ++r) {
#pragma unroll
    for (int k = 0; k < 4; ++k) {
      const int c  = 256 * w + 64 * k + l;
      const int cs = c ^ ((c >> 3) & 7);
      *reinterpret_cast<float4*>(&lds[r][cs * 4]) = st[r][k];
    }
  }
  wave_lds_fence();

  // ---- phase-1 fragment read, rows packed into float2 ----
  float2 v2[16];
#pragma unroll
  for (int k = 0; k < 4; ++k) {
    int ba = (t * 64 + k * 16) ^ (((t >> 1) & 7) << 4);  // swizzled byte addr
    float4 q0 = *reinterpret_cast<const float4*>(
        reinterpret_cast<const char*>(&lds[0][0]) + ba);
    float4 q1 = *reinterpret_cast<const float4*>(
        reinterpret_cast<const char*>(&lds[1][0]) + ba);
    v2[4 * k + 0] = make_float2(q0.x, q1.x);
    v2[4 * k + 1] = make_float2(q0.y, q1.y);
    v2[4 * k + 2] = make_float2(q0.z, q1.z);
    v2[4 * k + 3] = make_float2(q0.w, q1.w);
  }

  // ---- phase 1: stages 0..3 ----
  stage_math<TAB>(0, 0, qa0, qb0, ang, t, v2);
  stage_math<TAB>(1, 1, qa1, qb1, ang, t, v2);
  stage_math<TAB>(2, 2, qa2, qb2, ang, t, v2);
  stage_math<TAB>(3, 3, qa3, qb3, ang, t, v2);

  // ---- phase-2 table prefetch: L2 latency hides under exchange 1 ----
  uint4 pa0, pb0, pa1, pb1, pa2, pb2, pa3, pb3;
  fetch_stage<TAB>(tabq, 4, t, pa0, pb0);
  fetch_stage<TAB>(tabq, 5, t, pa1, pb1);
  fetch_stage<TAB>(tabq, 6, t, pa2, pb2);
  fetch_stage<TAB>(tabq, 7, t, pa3, pb3);

  // ---- exchange 1: REQUIRED block barrier (cross-view overlap, see note) ----
  block_barrier_lgkm();   // all waves done with staging + frag reads
#pragma unroll
  for (int j = 0; j < 16; ++j)
    ldsI[swzI(thi * 256 + j * 16 + tlo)] = v2[j];
  wave_lds_fence();       // exch-1 read region is wave-local to its writer
#pragma unroll
  for (int m = 0; m < 8; ++m) {
    float4 q = *reinterpret_cast<const float4*>(&ldsI[swzI(t * 16 + 2 * m)]);
    v2[2 * m + 0] = make_float2(q.x, q.y);
    v2[2 * m + 1] = make_float2(q.z, q.w);
  }

  // ---- phase 2: stages 4..7 ----
  stage_math<TAB>(4, 0, pa0, pb0, ang, t, v2);
  stage_math<TAB>(5, 1, pa1, pb1, ang, t, v2);
  stage_math<TAB>(6, 2, pa2, pb2, ang, t, v2);
  stage_math<TAB>(7, 3, pa3, pb3, ang, t, v2);

  // ---- exchange 2 (cross-wave): b64 writes to position j*256+tlo*16+thi ----
  block_barrier_lgkm();   // all waves done reading exchange-1 data
#pragma unroll
  for (int j = 0; j < 16; ++j)
    ldsI[swzI(j * 256 + tlo * 16 + thi)] = v2[j];

  // ---- phase-3 table prefetch: latency hides under barrier wait + reads ----
  uint4 ra0, rb0, ra1, rb1, ra2, rb2, ra3, rb3;
  fetch_stage<TAB>(tabq, 8, t, ra0, rb0);
  fetch_stage<TAB>(tabq, 9, t, ra1, rb1);
  fetch_stage<TAB>(tabq, 10, t, ra2, rb2);
  fetch_stage<TAB>(tabq, 11, t, ra3, rb3);

  block_barrier_lgkm();   // cross-writes visible
#pragma unroll
  for (int m = 0; m < 8; ++m) {
    float4 q = *reinterpret_cast<const float4*>(&ldsI[swzI(t * 16 + 2 * m)]);
    v2[2 * m + 0] = make_float2(q.x, q.y);
    v2[2 * m + 1] = make_float2(q.z, q.w);
  }

  // ---- phase 3: stages 8..11 ----
  stage_math<TAB>(8, 0, ra0, rb0, ang, t, v2);
  stage_math<TAB>(9, 1, ra1, rb1, ang, t, v2);
  stage_math<TAB>(10, 2, ra2, rb2, ang, t, v2);
  stage_math<TAB>(11, 3, ra3, rb3, ang, t, v2);

  // ---- store (elem i*256 + t: lanes contiguous, coalesced) ----
  float* orow0 = out + (row0 + 0) * NCOL;
  float* orow1 = out + (row0 + 1) * NCOL;
#pragma unroll
  for (int i = 0; i < 16; ++i) {
    orow0[i * 256 + t] = v2[i].x;
    orow1[i * 256 + t] = v2[i].y;
  }
}

extern "C" void kernel_launch(void* const* d_in, const int* in_sizes, int n_in,
                              void* d_out, int out_size, void* d_ws, size_t ws_size,
                              hipStream_t stream) {
  const float* x   = (const float*)d_in[0];
  const float* ang = (const float*)d_in[1];
  float* out       = (float*)d_out;

  const size_t tab_bytes = (size_t)NSTAGES * 2 * 256 * sizeof(uint4);  // 96 KB
  const int nblocks = NROWS / RPB;  // 8192

  if (ws_size >= tab_bytes) {
    uint4* tabq = (uint4*)d_ws;
    cs_table_kernel<<<(NSTAGES * 2 * 256 + 255) / 256, 256, 0, stream>>>(ang, tabq);
    butterfly_kernel<true><<<nblocks, 256, 0, stream>>>(x, tabq, nullptr, out);
  } else {
    butterfly_kernel<false><<<nblocks, 256, 0, stream>>>(x, nullptr, ang, out);
  }
}

// Round 14
// 94.504 us; speedup vs baseline: 4.3580x; 2.9280x over previous
//
#include <hip/hip_runtime.h>
#include <hip/hip_fp16.h>

#define NROWS   16384
#define NCOL    4096
#define NSTAGES 12
#define NPAIRS  2048
#define RPB     2   // rows per block (32 KB LDS) — R10 proven shape

// pair index needed by lane t, stage s, sub-pair p (matches butterfly layouts)
__device__ __forceinline__ int pair_idx(int s, int t, int p) {
  int thi = t >> 4, tlo = t & 15;
  return (s < 4) ? (t * 8 + p) : (s < 8) ? (thi * 128 + p * 16 + tlo) : (p * 256 + t);
}

// LDS bank swizzles for the two exchanges (validated R1-R10)
__device__ __forceinline__ int swz1(int W) {
  return W ^ (((W >> 8) & 1) << 4) ^ (((W >> 5) & 3) << 2);
}
__device__ __forceinline__ int swz2(int W) {
  return W ^ (((W >> 7) & 1) << 4) ^ (((W >> 5) & 3) << 2);
}

// fp16 packed table: tabq[(s*2+h)*256 + t] = uint4 of 4 half2 {cos,sin},
// pairs p = 4h..4h+3 for lane t, stage s. fp16 accuracy validated R6-R13
// (absmax 0.031 < 0.1175 threshold).
__global__ void cs_table_kernel(const float* __restrict__ ang, uint4* __restrict__ tabq) {
  int tid = blockIdx.x * blockDim.x + threadIdx.x;
  if (tid >= NSTAGES * 2 * 256) return;
  int s = tid >> 9;
  int h = (tid >> 8) & 1;
  int t = tid & 255;
  unsigned r[4];
#pragma unroll
  for (int e = 0; e < 4; ++e) {
    int pr = pair_idx(s, t, 4 * h + e);
    float sv, cv;
    sincosf(ang[s * NPAIRS + pr], &sv, &cv);
    __half2 hh = __floats2half2_rn(cv, sv);
    r[e] = *reinterpret_cast<unsigned*>(&hh);
  }
  tabq[tid] = make_uint4(r[0], r[1], r[2], r[3]);
}

__device__ __forceinline__ float2 h2f(unsigned u) {
  __half2 h = *reinterpret_cast<__half2*>(&u);
  return __half22float2(h);
}

// wave-lockstep LDS fence (validated R5-R10)
__device__ __forceinline__ void wave_lds_fence() {
  asm volatile("s_waitcnt lgkmcnt(0)" ::: "memory");
  __builtin_amdgcn_sched_barrier(0);
}

// block barrier WITHOUT vmcnt drain (validated R6-R10)
__device__ __forceinline__ void block_barrier_lgkm() {
  asm volatile("s_waitcnt lgkmcnt(0)" ::: "memory");
  __builtin_amdgcn_sched_barrier(0);
  __builtin_amdgcn_s_barrier();
  __builtin_amdgcn_sched_barrier(0);
}

// table prefetch for one stage (2 dwordx4); no-op in fallback mode
template <bool TAB>
__device__ __forceinline__ void fetch_stage(const uint4* __restrict__ tabq, int s, int t,
                                            uint4& qa, uint4& qb) {
  if constexpr (TAB) {
    qa = tabq[(s * 2 + 0) * 256 + t];
    qb = tabq[(s * 2 + 1) * 256 + t];
  }
}

// one butterfly stage on 2 rows packed as float2 (SLP-vectorizable f32 pairs)
template <bool TAB>
__device__ __forceinline__ void stage_math(int sg, int sl, uint4 qa, uint4 qb,
                                           const float* __restrict__ ang, int t,
                                           float2* v2) {
  const int d = 1 << sl;
  const unsigned aw[8] = {qa.x, qa.y, qa.z, qa.w, qb.x, qb.y, qb.z, qb.w};
#pragma unroll
  for (int p = 0; p < 8; ++p) {
    float2 A;
    if constexpr (TAB) {
      A = h2f(aw[p]);
    } else {
      float sv, cv;
      sincosf(ang[sg * NPAIRS + pair_idx(sg, t, p)], &sv, &cv);
      A = make_float2(cv, sv);
    }
    const int j0 = ((p >> sl) << (sl + 1)) | (p & (d - 1));
    const int j1 = j0 + d;
    float2 v0 = v2[j0], v1 = v2[j1];
    v2[j0] = make_float2(A.x * v0.x - A.y * v1.x, A.x * v0.y - A.y * v1.y);
    v2[j1] = make_float2(A.y * v0.x + A.x * v1.x, A.y * v0.y + A.x * v1.y);
  }
}

template <bool TAB>
__global__ __launch_bounds__(256, 4) void butterfly_kernel(
    const float* __restrict__ x, const uint4* __restrict__ tabq,
    const float* __restrict__ ang, float* __restrict__ out) {
  __shared__ __align__(16) float lds[RPB][NCOL];

  const int t   = threadIdx.x;
  const int w   = t >> 6;   // wave id
  const int l   = t & 63;   // lane id
  const int thi = t >> 4;
  const int tlo = t & 15;
  const size_t row0 = (size_t)blockIdx.x * RPB;

  // ---- staging global loads FIRST (oldest vmcnt entries) ----
  float4 st[RPB][4];
#pragma unroll
  for (int r = 0; r < RPB; ++r) {
    const float4* row4 = reinterpret_cast<const float4*>(x + (row0 + r) * NCOL);
#pragma unroll
    for (int k = 0; k < 4; ++k)
      st[r][k] = row4[256 * w + 64 * k + l];
  }

  // ---- phase-1 table prefetch: overlaps staging HBM latency ----
  uint4 qa0, qb0, qa1, qb1, qa2, qb2, qa3, qb3;
  fetch_stage<TAB>(tabq, 0, t, qa0, qb0);
  fetch_stage<TAB>(tabq, 1, t, qa1, qb1);
  fetch_stage<TAB>(tabq, 2, t, qa2, qb2);
  fetch_stage<TAB>(tabq, 3, t, qa3, qb3);

  // ---- stage to LDS: wave-local, swizzled sigma(c)=c^((c>>3)&7) ----
#pragma unroll
  for (int r = 0; r < RPB; ++r) {
#pragma unroll
    for (int k = 0; k < 4; ++k) {
      const int c  = 256 * w + 64 * k + l;
      const int cs = c ^ ((c >> 3) & 7);
      *reinterpret_cast<float4*>(&lds[r][cs * 4]) = st[r][k];
    }
  }
  wave_lds_fence();

  // ---- phase-1 fragment read, rows packed into float2 ----
  float2 v2[16];
#pragma unroll
  for (int k = 0; k < 4; ++k) {
    int ba = (t * 64 + k * 16) ^ (((t >> 1) & 7) << 4);  // swizzled byte addr
    float4 q0 = *reinterpret_cast<const float4*>(
        reinterpret_cast<const char*>(&lds[0][0]) + ba);
    float4 q1 = *reinterpret_cast<const float4*>(
        reinterpret_cast<const char*>(&lds[1][0]) + ba);
    v2[4 * k + 0] = make_float2(q0.x, q1.x);
    v2[4 * k + 1] = make_float2(q0.y, q1.y);
    v2[4 * k + 2] = make_float2(q0.z, q1.z);
    v2[4 * k + 3] = make_float2(q0.w, q1.w);
  }

  // ---- phase 1: stages 0..3 ----
  stage_math<TAB>(0, 0, qa0, qb0, ang, t, v2);
  stage_math<TAB>(1, 1, qa1, qb1, ang, t, v2);
  stage_math<TAB>(2, 2, qa2, qb2, ang, t, v2);
  stage_math<TAB>(3, 3, qa3, qb3, ang, t, v2);

  // ---- phase-2 table prefetch: L2 latency hides under exchange 1 ----
  uint4 pa0, pb0, pa1, pb1, pa2, pb2, pa3, pb3;
  fetch_stage<TAB>(tabq, 4, t, pa0, pb0);
  fetch_stage<TAB>(tabq, 5, t, pa1, pb1);
  fetch_stage<TAB>(tabq, 6, t, pa2, pb2);
  fetch_stage<TAB>(tabq, 7, t, pa3, pb3);

  // ---- exchange 1 (wave-local: quarter n[11:10]=w) ----
#pragma unroll
  for (int j = 0; j < 16; ++j) {
    lds[0][swz1(thi * 256 + j * 16 + tlo)] = v2[j].x;
    lds[1][swz1(thi * 256 + j * 16 + tlo)] = v2[j].y;
  }
  wave_lds_fence();
#pragma unroll
  for (int k = 0; k < 4; ++k) {
    float4 q0 = *reinterpret_cast<const float4*>(&lds[0][swz1(thi * 256 + tlo * 16 + 4 * k)]);
    float4 q1 = *reinterpret_cast<const float4*>(&lds[1][swz1(thi * 256 + tlo * 16 + 4 * k)]);
    v2[4 * k + 0] = make_float2(q0.x, q1.x);
    v2[4 * k + 1] = make_float2(q0.y, q1.y);
    v2[4 * k + 2] = make_float2(q0.z, q1.z);
    v2[4 * k + 3] = make_float2(q0.w, q1.w);
  }

  // ---- phase 2: stages 4..7 ----
  stage_math<TAB>(4, 0, pa0, pb0, ang, t, v2);
  stage_math<TAB>(5, 1, pa1, pb1, ang, t, v2);
  stage_math<TAB>(6, 2, pa2, pb2, ang, t, v2);
  stage_math<TAB>(7, 3, pa3, pb3, ang, t, v2);

  // ---- exchange 2 (cross-wave): raw barriers, no vmcnt drain ----
  block_barrier_lgkm();   // all waves done reading exchange-1 data
#pragma unroll
  for (int j = 0; j < 16; ++j) {
    lds[0][swz2(j * 256 + tlo * 16 + thi)] = v2[j].x;
    lds[1][swz2(j * 256 + tlo * 16 + thi)] = v2[j].y;
  }

  // ---- phase-3 table prefetch: latency hides under barrier wait + reads ----
  uint4 ra0, rb0, ra1, rb1, ra2, rb2, ra3, rb3;
  fetch_stage<TAB>(tabq, 8, t, ra0, rb0);
  fetch_stage<TAB>(tabq, 9, t, ra1, rb1);
  fetch_stage<TAB>(tabq, 10, t, ra2, rb2);
  fetch_stage<TAB>(tabq, 11, t, ra3, rb3);

  block_barrier_lgkm();   // cross-writes visible
#pragma unroll
  for (int k = 0; k < 4; ++k) {
    float4 q0 = *reinterpret_cast<const float4*>(&lds[0][swz2(thi * 256 + tlo * 16 + 4 * k)]);
    float4 q1 = *reinterpret_cast<const float4*>(&lds[1][swz2(thi * 256 + tlo * 16 + 4 * k)]);
    v2[4 * k + 0] = make_float2(q0.x, q1.x);
    v2[4 * k + 1] = make_float2(q0.y, q1.y);
    v2[4 * k + 2] = make_float2(q0.z, q1.z);
    v2[4 * k + 3] = make_float2(q0.w, q1.w);
  }

  // ---- phase 3: stages 8..11 ----
  stage_math<TAB>(8, 0, ra0, rb0, ang, t, v2);
  stage_math<TAB>(9, 1, ra1, rb1, ang, t, v2);
  stage_math<TAB>(10, 2, ra2, rb2, ang, t, v2);
  stage_math<TAB>(11, 3, ra3, rb3, ang, t, v2);

  // ---- store: non-temporal (output is write-once; keep L3 for input x) ----
  float* orow0 = out + (row0 + 0) * NCOL;
  float* orow1 = out + (row0 + 1) * NCOL;
#pragma unroll
  for (int i = 0; i < 16; ++i) {
    __builtin_nontemporal_store(v2[i].x, &orow0[i * 256 + t]);
    __builtin_nontemporal_store(v2[i].y, &orow1[i * 256 + t]);
  }
}

extern "C" void kernel_launch(void* const* d_in, const int* in_sizes, int n_in,
                              void* d_out, int out_size, void* d_ws, size_t ws_size,
                              hipStream_t stream) {
  const float* x   = (const float*)d_in[0];
  const float* ang = (const float*)d_in[1];
  float* out       = (float*)d_out;

  const size_t tab_bytes = (size_t)NSTAGES * 2 * 256 * sizeof(uint4);  // 96 KB
  const int nblocks = NROWS / RPB;  // 8192

  if (ws_size >= tab_bytes) {
    uint4* tabq = (uint4*)d_ws;
    cs_table_kernel<<<(NSTAGES * 2 * 256 + 255) / 256, 256, 0, stream>>>(ang, tabq);
    butterfly_kernel<true><<<nblocks, 256, 0, stream>>>(x, tabq, nullptr, out);
  } else {
    butterfly_kernel<false><<<nblocks, 256, 0, stream>>>(x, nullptr, ang, out);
  }
}